// Round 3
// baseline (820.942 us; speedup 1.0000x reference)
//
#include <hip/hip_runtime.h>
#include <math.h>

// GCN 2-layer: x[N,128] @ W1 -> scatter(norm) -> relu -> @ W2 -> scatter(norm)
//   -> +b2 -> log_softmax.  norm = dinv[row]*dinv[col], deg over targets incl
//   self-loop.  Reformulated: agg[c] = dinv[c]*(sum_{e:col=c} hs[row[e]] + hs[c]),
//   hs[i] = dinv[i]*(h[i]@W).  Self-loop folded in as accumulator init.
// edge_index: harness converts int64 -> int32 (R2 OOB crash proved 8E-byte buffer).
#define F_IN  128
#define F_HID 16
#define F_OUT 32

__global__ void k_init_deg(float* deg, int N) {
    int i = blockIdx.x * blockDim.x + threadIdx.x;
    if (i < N) deg[i] = 1.0f;  // self-loop contribution
}

__global__ void k_count_deg(const int* __restrict__ col, int E, float* deg) {
    int i = blockIdx.x * blockDim.x + threadIdx.x;
    if (i < E) atomicAdd(&deg[col[i]], 1.0f);
}

__global__ void k_rsqrt(float* deg, int N) {
    int i = blockIdx.x * blockDim.x + threadIdx.x;
    if (i < N) deg[i] = rsqrtf(deg[i]);  // deg >= 1 always (self-loop)
}

// 16 nodes x 16 out-ch per 256-thread block. x tile + W1 staged in LDS.
__global__ void k_gemm1(const float* __restrict__ x, const float* __restrict__ W1,
                        const float* __restrict__ dinv,
                        float* __restrict__ hs1, float* __restrict__ acc1, int N) {
    __shared__ float sW[F_IN * F_HID];     // 2048 floats, strided load
    __shared__ float sX[16][F_IN + 1];     // +1 pad: avoid bank conflict
    int t = threadIdx.x;
    for (int k = t; k < F_IN * F_HID; k += 256) sW[k] = W1[k];
    int node0 = blockIdx.x * 16;
    for (int k = t; k < 16 * F_IN; k += 256) {
        int r = k / F_IN, c = k % F_IN;
        int n = node0 + r;
        sX[r][c] = (n < N) ? x[(size_t)node0 * F_IN + k] : 0.f;
    }
    __syncthreads();
    int il = t >> 4, j = t & 15;
    float acc = 0.f;
    const float* xr = sX[il];
#pragma unroll 8
    for (int k = 0; k < F_IN; ++k) acc += xr[k] * sW[k * F_HID + j];
    int n = node0 + il;
    if (n < N) {
        float v = acc * dinv[n];
        size_t o = (size_t)n * F_HID + j;
        hs1[o] = v;
        acc1[o] = v;  // self-loop term
    }
}

// one thread per (edge, channel); gather coalesced over j, scatter atomic.
__global__ void k_scatter1(const int* __restrict__ row, const int* __restrict__ col,
                           const float* __restrict__ hs1, float* __restrict__ acc1,
                           int E) {
    int idx = blockIdx.x * blockDim.x + threadIdx.x;
    if (idx >= E * F_HID) return;
    int e = idx >> 4, j = idx & 15;
    int r = row[e], c = col[e];
    atomicAdd(&acc1[(size_t)c * F_HID + j], hs1[(size_t)r * F_HID + j]);
}

__global__ void k_relu1(float* __restrict__ acc1, const float* __restrict__ dinv,
                        const float* __restrict__ b1, int N) {
    int idx = blockIdx.x * blockDim.x + threadIdx.x;
    if (idx >= N * F_HID) return;
    int n = idx >> 4, j = idx & 15;
    float v = dinv[n] * acc1[idx] + b1[j];
    acc1[idx] = v > 0.f ? v : 0.f;   // acc1 becomes h1 in place
}

// 8 nodes x 32 out-ch per 256-thread block.
__global__ void k_gemm2(const float* __restrict__ h1, const float* __restrict__ W2,
                        const float* __restrict__ dinv,
                        float* __restrict__ hs2, float* __restrict__ acc2, int N) {
    __shared__ float sW[F_HID * F_OUT];  // 512 floats — STRIDED load (R1 bug: only 256 loaded)
    __shared__ float sH[8 * F_HID];      // 128 floats
    int t = threadIdx.x;
    for (int k = t; k < F_HID * F_OUT; k += 256) sW[k] = W2[k];
    int node0 = blockIdx.x * 8;
    if (t < 8 * F_HID) {
        int n = node0 + t / F_HID;
        sH[t] = (n < N) ? h1[(size_t)node0 * F_HID + t] : 0.f;
    }
    __syncthreads();
    int il = t >> 5, j = t & 31;
    float acc = 0.f;
#pragma unroll
    for (int k = 0; k < F_HID; ++k) acc += sH[il * F_HID + k] * sW[k * F_OUT + j];
    int n = node0 + il;
    if (n < N) {
        float v = acc * dinv[n];
        size_t o = (size_t)n * F_OUT + j;
        hs2[o] = v;
        acc2[o] = v;
    }
}

__global__ void k_scatter2(const int* __restrict__ row, const int* __restrict__ col,
                           const float* __restrict__ hs2, float* __restrict__ acc2,
                           int E) {
    int idx = blockIdx.x * blockDim.x + threadIdx.x;
    if (idx >= E * F_OUT) return;
    int e = idx >> 5, j = idx & 31;
    int r = row[e], c = col[e];
    atomicAdd(&acc2[(size_t)c * F_OUT + j], hs2[(size_t)r * F_OUT + j]);
}

// bias + log_softmax; 8 nodes x 32 lanes per block, shuffle reduce width 32.
__global__ void k_final(const float* __restrict__ acc2, const float* __restrict__ dinv,
                        const float* __restrict__ b2, float* __restrict__ out, int N) {
    int t = threadIdx.x;
    int il = t >> 5, j = t & 31;
    int n = blockIdx.x * 8 + il;
    if (n >= N) return;
    float v = dinv[n] * acc2[(size_t)n * F_OUT + j] + b2[j];
    float m = v;
    for (int off = 16; off > 0; off >>= 1) m = fmaxf(m, __shfl_xor(m, off, 32));
    float ex = __expf(v - m);
    float s = ex;
    for (int off = 16; off > 0; off >>= 1) s += __shfl_xor(s, off, 32);
    out[(size_t)n * F_OUT + j] = v - m - __logf(s);
}

extern "C" void kernel_launch(void* const* d_in, const int* in_sizes, int n_in,
                              void* d_out, int out_size, void* d_ws, size_t ws_size,
                              hipStream_t stream) {
    const float* x  = (const float*)d_in[0];
    const int*   ei = (const int*)d_in[1];   // [2, E] int32 (harness-converted)
    const float* W1 = (const float*)d_in[2];
    const float* b1 = (const float*)d_in[3];
    const float* W2 = (const float*)d_in[4];
    const float* b2 = (const float*)d_in[5];
    float* out = (float*)d_out;

    int N = in_sizes[0] / F_IN;
    int E = in_sizes[1] / 2;
    const int* row = ei;       // sources
    const int* col = ei + E;   // targets

    // workspace layout (floats): dinv[N] | hs1[N*16] | acc1[N*16] | hs2[N*32] | acc2[N*32]
    float* ws   = (float*)d_ws;
    float* dinv = ws;
    float* hs1  = dinv + N;
    float* acc1 = hs1 + (size_t)N * F_HID;
    float* hs2  = acc1 + (size_t)N * F_HID;
    float* acc2 = hs2 + (size_t)N * F_OUT;

    k_init_deg<<<(N + 255) / 256, 256, 0, stream>>>(dinv, N);
    k_count_deg<<<(E + 255) / 256, 256, 0, stream>>>(col, E, dinv);
    k_rsqrt<<<(N + 255) / 256, 256, 0, stream>>>(dinv, N);

    k_gemm1<<<(N + 15) / 16, 256, 0, stream>>>(x, W1, dinv, hs1, acc1, N);
    {
        long long tot = (long long)E * F_HID;
        k_scatter1<<<(unsigned)((tot + 255) / 256), 256, 0, stream>>>(row, col, hs1, acc1, E);
    }
    k_relu1<<<((long long)N * F_HID + 255) / 256, 256, 0, stream>>>(acc1, dinv, b1, N);

    k_gemm2<<<(N + 7) / 8, 256, 0, stream>>>(acc1, W2, dinv, hs2, acc2, N);
    {
        long long tot = (long long)E * F_OUT;
        k_scatter2<<<(unsigned)((tot + 255) / 256), 256, 0, stream>>>(row, col, hs2, acc2, E);
    }
    k_final<<<(N + 7) / 8, 256, 0, stream>>>(acc2, dinv, b2, out, N);
}

// Round 4
// 816.571 us; speedup vs baseline: 1.0054x; 1.0054x over previous
//
#include <hip/hip_runtime.h>
#include <math.h>

// GCN 2-layer, CSR-gather formulation (no fp32 atomics):
//   R3 profile: atomic scatter WRITE_SIZE == #atomics*4B (write-through to HBM),
//   617 MB HBM traffic on scatter2 alone. Fix: build CSR per launch (int
//   histogram + scan + fill), then per-node gather-sum from L2/L3-resident hs.
//   agg[c] = dinv[c]*(sum_{e: col=c} hs[srcs[e]] + hs[c]),  hs[i]=dinv[i]*(h[i]@W)
// edge_index: harness converts int64 -> int32 (R2 OOB crash proved 8E buffer).
#define F_IN  128
#define F_HID 16
#define F_OUT 32
#define CHUNK 1024

__global__ void k_zero_i(int* p, int n) {
    int i = blockIdx.x * blockDim.x + threadIdx.x;
    if (i < n) p[i] = 0;
}

__global__ void k_hist(const int* __restrict__ col, int E, int* __restrict__ cnt) {
    int i = blockIdx.x * blockDim.x + threadIdx.x;
    if (i < E) atomicAdd(&cnt[col[i]], 1);
}

__global__ void k_dinv(const int* __restrict__ cnt, float* __restrict__ dinv, int N) {
    int i = blockIdx.x * blockDim.x + threadIdx.x;
    if (i < N) dinv[i] = rsqrtf((float)cnt[i] + 1.0f);  // +1 = self-loop
}

// exclusive scan, 1024 elems/block (256 thr x 4): per-chunk prefix + block sums
__global__ void k_scan1(const int* __restrict__ cnt, int* __restrict__ ptr,
                        int* __restrict__ bsum, int N) {
    __shared__ int sd[256];
    int t = threadIdx.x;
    int base = blockIdx.x * CHUNK + t * 4;
    int v[4], ts = 0;
#pragma unroll
    for (int k = 0; k < 4; ++k) { v[k] = (base + k < N) ? cnt[base + k] : 0; ts += v[k]; }
    sd[t] = ts;
    __syncthreads();
    for (int off = 1; off < 256; off <<= 1) {
        int x = (t >= off) ? sd[t - off] : 0;
        __syncthreads();
        sd[t] += x;
        __syncthreads();
    }
    int run = sd[t] - ts;  // exclusive prefix of this thread within chunk
    if (t == 255) bsum[blockIdx.x] = sd[255];
#pragma unroll
    for (int k = 0; k < 4; ++k) {
        if (base + k < N) ptr[base + k] = run;
        run += v[k];
    }
}

__global__ void k_scan2(int* __restrict__ bsum, int NB) {  // single block, NB<=256
    __shared__ int sd[256];
    int t = threadIdx.x;
    int v = (t < NB) ? bsum[t] : 0;
    sd[t] = v;
    __syncthreads();
    for (int off = 1; off < 256; off <<= 1) {
        int x = (t >= off) ? sd[t - off] : 0;
        __syncthreads();
        sd[t] += x;
        __syncthreads();
    }
    if (t < NB) bsum[t] = sd[t] - v;  // exclusive
}

__global__ void k_scan3(int* __restrict__ ptr, const int* __restrict__ bsum,
                        int N, int E) {
    int i = blockIdx.x * blockDim.x + threadIdx.x;
    if (i < N) ptr[i] += bsum[i / CHUNK];
    if (i == 0) ptr[N] = E;
}

__global__ void k_copy_i(const int* __restrict__ a, int* __restrict__ b, int n) {
    int i = blockIdx.x * blockDim.x + threadIdx.x;
    if (i < n) b[i] = a[i];
}

__global__ void k_fill(const int* __restrict__ row, const int* __restrict__ col,
                       int* __restrict__ cur, int* __restrict__ srcs, int E) {
    int e = blockIdx.x * blockDim.x + threadIdx.x;
    if (e < E) {
        int p = atomicAdd(&cur[col[e]], 1);
        srcs[p] = row[e];
    }
}

// 16 nodes x 16 out-ch per 256-thread block. x tile + W1 staged in LDS.
__global__ void k_gemm1(const float* __restrict__ x, const float* __restrict__ W1,
                        const float* __restrict__ dinv, float* __restrict__ hs1, int N) {
    __shared__ float sW[F_IN * F_HID];
    __shared__ float sX[16][F_IN + 1];
    int t = threadIdx.x;
    for (int k = t; k < F_IN * F_HID; k += 256) sW[k] = W1[k];
    int node0 = blockIdx.x * 16;
    for (int k = t; k < 16 * F_IN; k += 256) {
        int r = k / F_IN, c = k % F_IN;
        int n = node0 + r;
        sX[r][c] = (n < N) ? x[(size_t)node0 * F_IN + k] : 0.f;
    }
    __syncthreads();
    int il = t >> 4, j = t & 15;
    float acc = 0.f;
    const float* xr = sX[il];
#pragma unroll 8
    for (int k = 0; k < F_IN; ++k) acc += xr[k] * sW[k * F_HID + j];
    int n = node0 + il;
    if (n < N) hs1[(size_t)n * F_HID + j] = acc * dinv[n];
}

// per-node gather over incoming edges; 16 lanes/node; fused dinv+bias+relu.
__global__ void k_gather1(const float* __restrict__ hs1, const int* __restrict__ ptr,
                          const int* __restrict__ srcs, const float* __restrict__ dinv,
                          const float* __restrict__ b1, float* __restrict__ h1, int N) {
    int t = threadIdx.x;
    int n = blockIdx.x * 16 + (t >> 4);
    int j = t & 15;
    if (n >= N) return;
    float acc = hs1[(size_t)n * F_HID + j];  // self-loop
    int e0 = ptr[n], e1 = ptr[n + 1];
    for (int e = e0; e < e1; ++e)
        acc += hs1[(size_t)srcs[e] * F_HID + j];
    float v = dinv[n] * acc + b1[j];
    h1[(size_t)n * F_HID + j] = v > 0.f ? v : 0.f;
}

// 8 nodes x 32 out-ch per 256-thread block.
__global__ void k_gemm2(const float* __restrict__ h1, const float* __restrict__ W2,
                        const float* __restrict__ dinv, float* __restrict__ hs2, int N) {
    __shared__ float sW[F_HID * F_OUT];  // 512 floats, strided load
    __shared__ float sH[8 * F_HID];
    int t = threadIdx.x;
    for (int k = t; k < F_HID * F_OUT; k += 256) sW[k] = W2[k];
    int node0 = blockIdx.x * 8;
    if (t < 8 * F_HID) {
        int n = node0 + t / F_HID;
        sH[t] = (n < N) ? h1[(size_t)node0 * F_HID + t] : 0.f;
    }
    __syncthreads();
    int il = t >> 5, j = t & 31;
    float acc = 0.f;
#pragma unroll
    for (int k = 0; k < F_HID; ++k) acc += sH[il * F_HID + k] * sW[k * F_OUT + j];
    int n = node0 + il;
    if (n < N) hs2[(size_t)n * F_OUT + j] = acc * dinv[n];
}

// gather + dinv + bias + log_softmax fused; 32 lanes/node, shuffle reductions.
__global__ void k_gather2_final(const float* __restrict__ hs2, const int* __restrict__ ptr,
                                const int* __restrict__ srcs, const float* __restrict__ dinv,
                                const float* __restrict__ b2, float* __restrict__ out, int N) {
    int t = threadIdx.x;
    int n = blockIdx.x * 8 + (t >> 5);
    int j = t & 31;
    if (n >= N) return;
    float acc = hs2[(size_t)n * F_OUT + j];  // self-loop
    int e0 = ptr[n], e1 = ptr[n + 1];
    for (int e = e0; e < e1; ++e)
        acc += hs2[(size_t)srcs[e] * F_OUT + j];
    float v = dinv[n] * acc + b2[j];
    float m = v;
    for (int off = 16; off > 0; off >>= 1) m = fmaxf(m, __shfl_xor(m, off, 32));
    float s = __expf(v - m);
    for (int off = 16; off > 0; off >>= 1) s += __shfl_xor(s, off, 32);
    out[(size_t)n * F_OUT + j] = v - m - __logf(s);
}

extern "C" void kernel_launch(void* const* d_in, const int* in_sizes, int n_in,
                              void* d_out, int out_size, void* d_ws, size_t ws_size,
                              hipStream_t stream) {
    const float* x  = (const float*)d_in[0];
    const int*   ei = (const int*)d_in[1];   // [2, E] int32 (harness-converted)
    const float* W1 = (const float*)d_in[2];
    const float* b1 = (const float*)d_in[3];
    const float* W2 = (const float*)d_in[4];
    const float* b2 = (const float*)d_in[5];
    float* out = (float*)d_out;

    int N = in_sizes[0] / F_IN;
    int E = in_sizes[1] / 2;
    const int* row = ei;       // sources
    const int* col = ei + E;   // targets
    int NB = (N + CHUNK - 1) / CHUNK;   // scan blocks (98 for N=100k, <=256 ok)

    // ws layout (4B units): dinv[N] f | ptr[N+1] i | cur[N] i | bsum[256] i |
    //                       srcs[E] i | hs1[16N] f | h1[16N] f | hs2[32N] f
    char* w = (char*)d_ws;
    float* dinv = (float*)w;                w += sizeof(float) * N;
    int*   ptr  = (int*)w;                  w += sizeof(int) * (N + 1);
    int*   cur  = (int*)w;                  w += sizeof(int) * N;
    int*   bsum = (int*)w;                  w += sizeof(int) * 256;
    int*   srcs = (int*)w;                  w += sizeof(int) * E;
    float* hs1  = (float*)w;                w += sizeof(float) * (size_t)N * F_HID;
    float* h1   = (float*)w;                w += sizeof(float) * (size_t)N * F_HID;
    float* hs2  = (float*)w;

    // --- CSR build ---
    k_zero_i<<<(N + 255) / 256, 256, 0, stream>>>(cur, N);
    k_hist<<<(E + 255) / 256, 256, 0, stream>>>(col, E, cur);
    k_dinv<<<(N + 255) / 256, 256, 0, stream>>>(cur, dinv, N);
    k_scan1<<<NB, 256, 0, stream>>>(cur, ptr, bsum, N);
    k_scan2<<<1, 256, 0, stream>>>(bsum, NB);
    k_scan3<<<(N + 255) / 256, 256, 0, stream>>>(ptr, bsum, N, E);
    k_copy_i<<<(N + 255) / 256, 256, 0, stream>>>(ptr, cur, N);
    k_fill<<<(E + 255) / 256, 256, 0, stream>>>(row, col, cur, srcs, E);

    // --- layer 1 ---
    k_gemm1<<<(N + 15) / 16, 256, 0, stream>>>(x, W1, dinv, hs1, N);
    k_gather1<<<(N + 15) / 16, 256, 0, stream>>>(hs1, ptr, srcs, dinv, b1, h1, N);

    // --- layer 2 + epilogue ---
    k_gemm2<<<(N + 7) / 8, 256, 0, stream>>>(h1, W2, dinv, hs2, N);
    k_gather2_final<<<(N + 7) / 8, 256, 0, stream>>>(hs2, ptr, srcs, dinv, b2, out, N);
}